// Round 9
// baseline (3722.391 us; speedup 1.0000x reference)
//
#include <hip/hip_runtime.h>
#include <cstdint>
#include <cstddef>

// ---------------------------------------------------------------------------
// RNNModel: 2-layer bidirectional GRU (B=64, T=1000, H=256) + FC(512->61) +
// length-gather.
// Round 13 = Round 12 (1395us/dispatch) + two work cuts:
//  - GRU z/n acc-init: acc[*][1] initialized with gi_z, acc[*][2] with scaled
//    bhh_n at the (unchanged-position) staged-gi fence; MFMA accumulates on
//    top. Removes 16 zero-inits + 16 adds per wave (~4% step). r-gate keeps
//    its add (its MFMA block runs before the fence by design).
//  - GEMM 2-phase staging: double-buffered LDS, stage(t+1) issued BEFORE
//    compute(t), ONE __syncthreads per K-step (was 2 with DMA latency fully
//    exposed). Tail stage reads land in workspace slack (verified).
// Base unchanged: unit-pair permutation pi, 36 pinned W frags + 12/wave LDS,
// gate-split MFMA wall with interleaved trans chains, LDS-staged gi (GEMM
// writes GRU-native layout), h dbuf single barrier, exp2-prescaled gates,
// counted vmcnt(4) fence, packed u32 h writes / coalesced dword hout.
// ---------------------------------------------------------------------------

typedef __attribute__((ext_vector_type(8))) __bf16 bf16x8;
typedef __attribute__((ext_vector_type(4))) float f32x4;
typedef __attribute__((ext_vector_type(4))) unsigned int u32x4;

#define AS1 __attribute__((address_space(1)))
#define AS3 __attribute__((address_space(3)))

#define LOG2E 1.44269504089f
#define SRZ  (-1.44269504089f)   // scale for r,z rows
#define SN   (2.88539008177f)    // scale for n rows

__device__ __forceinline__ void async_ld16(const void* g, void* l) {
  __builtin_amdgcn_global_load_lds((const AS1 unsigned int*)g,
                                   (AS3 unsigned int*)l, 16, 0, 0);
}

__device__ __forceinline__ f32x4 mfma16(u32x4 a, u32x4 b, f32x4 c) {
  return __builtin_amdgcn_mfma_f32_16x16x32_bf16(
      __builtin_bit_cast(bf16x8, a), __builtin_bit_cast(bf16x8, b), c, 0, 0, 0);
}

__device__ __forceinline__ unsigned short f2b(float f) {  // f32 -> bf16 RNE
  unsigned int u = __float_as_uint(f);
  u += 0x7fffu + ((u >> 16) & 1u);
  return (unsigned short)(u >> 16);
}
__device__ __forceinline__ float b2f(unsigned short s) {
  return __uint_as_float(((unsigned int)s) << 16);
}
// packed f32 pair -> 2x bf16 in one u32 (lo = first arg), RNE
__device__ __forceinline__ unsigned int cvtpk(float lo, float hi) {
  unsigned int r;
  asm("v_cvt_pk_bf16_f32 %0, %1, %2" : "=v"(r) : "v"(lo), "v"(hi));
  return r;
}
__device__ __forceinline__ float lo16(unsigned int d) {
  return __uint_as_float(d << 16);
}
__device__ __forceinline__ float hi16(unsigned int d) {
  return __uint_as_float(d & 0xffff0000u);
}
__device__ __forceinline__ float gload(const float* p, size_t i) { return p[i]; }
__device__ __forceinline__ float gload(const unsigned short* p, size_t i) { return b2f(p[i]); }

// pre-scaled gate helpers (inputs already multiplied by SRZ / SN)
__device__ __forceinline__ float sigm2(float xs) {  // sigma(x), xs = -log2e*x
  return __builtin_amdgcn_rcpf(1.0f + __builtin_amdgcn_exp2f(xs));
}
__device__ __forceinline__ float tanh2(float ys) {  // tanh(y), ys = 2log2e*y
  return __builtin_fmaf(-2.0f,
      __builtin_amdgcn_rcpf(1.0f + __builtin_amdgcn_exp2f(ys)), 1.0f);
}

// lgkm-only barrier: don't drain vmcnt (stores + staged-gi DMA stay in flight)
__device__ __forceinline__ void lds_barrier() {
  asm volatile("" ::: "memory");
  __builtin_amdgcn_s_waitcnt(0xC07F);  // vmcnt=63, expcnt=7, lgkmcnt=0
  __builtin_amdgcn_s_barrier();
  asm volatile("" ::: "memory");
}

// ---------------------------------------------------------------------------
__global__ void cast_bf16_kernel(const float* __restrict__ src,
                                 unsigned short* __restrict__ dst, int n) {
  const int i = blockIdx.x * 256 + threadIdx.x;
  if (i < n) dst[i] = f2b(src[i]);
}

// weight cast with per-gate-row exp2 prescale. rows: [0,512) r,z ; [512,768) n
__global__ void cast_w_kernel(const float* __restrict__ src,
                              unsigned short* __restrict__ dst, int n,
                              int in_dim) {
  const int i = blockIdx.x * 256 + threadIdx.x;
  if (i < n) {
    const int row = (i / in_dim) % 768;
    const float s = (row < 512) ? SRZ : SN;
    dst[i] = f2b(s * src[i]);
  }
}

// weight cast with K-dim unit-pair permutation: dst position p within each
// 256-group holds src k = w*32 + j*16 + c where p = w*32 + c*2 + j.
// scaled!=0: per-gate-row exp2 prescale (rows mod 768).
__global__ void cast_w_perm_kernel(const float* __restrict__ src,
                                   unsigned short* __restrict__ dst, int n,
                                   int in_dim, int scaled) {
  const int i = blockIdx.x * 256 + threadIdx.x;
  if (i < n) {
    const int row = i / in_dim;
    const int p = i - row * in_dim;
    const int hi = p >> 8, pr = p & 255;
    const int w = pr >> 5, c2 = pr & 31;
    const int k = hi * 256 + w * 32 + (c2 & 1) * 16 + (c2 >> 1);
    float s = 1.0f;
    if (scaled) s = ((row % 768) < 512) ? SRZ : SN;
    dst[i] = f2b(s * src[(size_t)row * in_dim + k]);
  }
}

// fused GEMM bias: scaled (b_ih + b_hh) for r,z rows; scaled b_ih for n rows
__global__ void bias_fuse_kernel(const float* __restrict__ bih,
                                 const float* __restrict__ bhh,
                                 float* __restrict__ fb) {
  const int n = blockIdx.x * 256 + threadIdx.x;  // 0..1535
  if (n < 1536) {
    const int dir = n >> 9 >> 1 ? 1 : (n / 768);  // n/768
    const int rr = n - dir * 768;
    const float s = (rr < 512) ? SRZ : SN;
    float v = bih[dir * 768 + rr];
    if (rr < 512) v += bhh[dir * 768 + rr];
    fb[n] = s * v;
  }
}

// batch [B,T,8,40] -> x [T,B,320] bf16, x[t,b,f*8+c] = batch[b,t,c,f]
__global__ void transpose_x_kernel(const float* __restrict__ batch,
                                   unsigned short* __restrict__ xb) {
  const int t = blockIdx.x, b = blockIdx.y, i = threadIdx.x;  // block 320
  const float v = batch[((size_t)b * 1000 + t) * 320 + (i & 7) * 40 + (i >> 3)];
  xb[((size_t)t * 64 + b) * 320 + i] = f2b(v);
}

// ---------------------------------------------------------------------------
// C = A[M,K](bf16) @ W[N,K](bf16)^T + bias[N]. 128x128 tile, BK=32, 256 thr.
// 2-phase double-buffered staging: stage(t+1) before compute(t), ONE sync per
// K-step (the sync's vmcnt(0)+lgkmcnt(0) drains stage + publishes reads).
// Last iteration stages K..K+32 — reads land in workspace slack (safe).
// PERM=false: C[M,N] row-major. PERM=true: GRU staged layout:
//   slot = t*64 + (sgrp*2+dir)*8 + ww,  ww = (unit/32) in 0..7
template <typename CT, bool PERM>
__global__ __launch_bounds__(256) void gemm_bt_kernel(
    const unsigned short* __restrict__ A, const unsigned short* __restrict__ W,
    const float* __restrict__ bias, CT* __restrict__ C, int M, int N, int K) {
  __shared__ __align__(16) unsigned short As[2][4096];
  __shared__ __align__(16) unsigned short Bs[2][4096];
  const int tid = threadIdx.x;
  const int lane = tid & 63;
  const int wv = tid >> 6;
  const int mBase = blockIdx.x * 128;
  const int nBase = blockIdx.y * 128;

  const int s0 = tid, s1 = tid + 256;
  const int r0 = ((s0 >> 6) << 4) | (s0 & 15), c0 = ((s0 >> 4) & 3) * 8;
  const int r1 = ((s1 >> 6) << 4) | (s1 & 15), c1 = ((s1 >> 4) & 3) * 8;

  const unsigned short* Arow0 = A + (size_t)(mBase + r0) * K + c0;
  const unsigned short* Arow1 = A + (size_t)(mBase + r1) * K + c1;
  const unsigned short* Wrow0 = W + (size_t)(nBase + r0) * K + c0;
  const unsigned short* Wrow1 = W + (size_t)(nBase + r1) * K + c1;

  auto stage = [&](int buf, int k0) {
    char* lA = (char*)As[buf];
    char* lB = (char*)Bs[buf];
    async_ld16(Arow0 + k0, lA + wv * 1024);
    async_ld16(Arow1 + k0, lA + 4096 + wv * 1024);
    async_ld16(Wrow0 + k0, lB + wv * 1024);
    async_ld16(Wrow1 + k0, lB + 4096 + wv * 1024);
  };

  f32x4 acc[4][4] = {};
  const int mh = (wv >> 1) * 64, nh = (wv & 1) * 64;

  stage(0, 0);
  __syncthreads();

  const int NT = K >> 5;
  for (int t = 0; t < NT; ++t) {
    const int cur = t & 1;
    stage(cur ^ 1, (t + 1) << 5);  // overlaps with compute below
    const u32x4* As4 = (const u32x4*)As[cur];
    const u32x4* Bs4 = (const u32x4*)Bs[cur];
    u32x4 a[4], b[4];
#pragma unroll
    for (int mt = 0; mt < 4; ++mt) a[mt] = As4[((mh >> 4) + mt) * 64 + lane];
#pragma unroll
    for (int nt = 0; nt < 4; ++nt) b[nt] = Bs4[((nh >> 4) + nt) * 64 + lane];
#pragma unroll
    for (int mt = 0; mt < 4; ++mt)
#pragma unroll
      for (int nt = 0; nt < 4; ++nt)
        acc[mt][nt] = mfma16(a[mt], b[nt], acc[mt][nt]);
    __syncthreads();  // drains stage DMA + ds_reads; publishes for next iter
  }

  if constexpr (PERM) {
    const int t = (mBase + mh) >> 6;  // mBase+mh multiple of 64
#pragma unroll
    for (int p = 0; p < 2; ++p) {  // nt pair (2p -> j=0, 2p+1 -> j=1)
      const int nb0 = nBase + nh + p * 32;
      const int dir = (nb0 >= 768) ? 1 : 0;
      const int np = nb0 - dir * 768;
      const int g = np >> 8;
      const int ww = (np >> 5) & 7;
      const float bn0 = bias[nb0 + (lane & 15)];
      const float bn1 = bias[nb0 + 16 + (lane & 15)];
#pragma unroll
      for (int mt = 0; mt < 4; ++mt) {  // sample group = mt
        const size_t slot = (size_t)t * 64 + (size_t)(mt * 2 + dir) * 8 + ww;
        if constexpr (sizeof(CT) == 2) {
          u32x4 v;
          v[0] = cvtpk(acc[mt][2 * p][0] + bn0, acc[mt][2 * p][1] + bn0);
          v[1] = cvtpk(acc[mt][2 * p][2] + bn0, acc[mt][2 * p][3] + bn0);
          v[2] = cvtpk(acc[mt][2 * p + 1][0] + bn1, acc[mt][2 * p + 1][1] + bn1);
          v[3] = cvtpk(acc[mt][2 * p + 1][2] + bn1, acc[mt][2 * p + 1][3] + bn1);
          *(u32x4*)((unsigned short*)C + slot * 1536 + (size_t)g * 512 +
                    (size_t)lane * 8) = v;
        } else {
#pragma unroll
          for (int rs = 0; rs < 2; ++rs) {
            f32x4 v = {acc[mt][2 * p][2 * rs] + bn0,
                       acc[mt][2 * p][2 * rs + 1] + bn0,
                       acc[mt][2 * p + 1][2 * rs] + bn1,
                       acc[mt][2 * p + 1][2 * rs + 1] + bn1};
            *(f32x4*)((float*)C + slot * 1536 + (size_t)(g * 2 + rs) * 256 +
                      (size_t)lane * 4) = v;
          }
        }
      }
    }
  } else {
#pragma unroll
    for (int nt = 0; nt < 4; ++nt) {
      const int n = nBase + nh + nt * 16 + (lane & 15);
      const float bn = bias[n];
#pragma unroll
      for (int mt = 0; mt < 4; ++mt) {
        const int mrow = mBase + mh + mt * 16 + ((lane >> 4) << 2);
#pragma unroll
        for (int r = 0; r < 4; ++r) {
          const float v = acc[mt][nt][r] + bn;
          if constexpr (sizeof(CT) == 2)
            ((unsigned short*)C)[(size_t)(mrow + r) * N + n] = f2b(v);
          else
            ((float*)C)[(size_t)(mrow + r) * N + n] = v;
        }
      }
    }
  }
}

// ---------------------------------------------------------------------------
// one MFMA gate-block: 12 pinned-frag MFMAs + 4 LDS-tail MFMAs, G is a literal
#define GBLOCK(G)                                                              \
  {                                                                            \
    _Pragma("unroll") for (int kt = 0; kt < 6; ++kt) {                         \
      acc[0][G] = mfma16(a[kt], wv[0][G][kt], acc[0][G]);                      \
      acc[1][G] = mfma16(a[kt], wv[1][G][kt], acc[1][G]);                      \
    }                                                                          \
    _Pragma("unroll") for (int kk = 0; kk < 2; ++kk) {                         \
      u32x4 bf0 = *(const u32x4*)(wlds +                                       \
          (((w * 12 + (0 * 3 + (G)) * 2 + kk) << 10) + lane * 16));            \
      u32x4 bf1 = *(const u32x4*)(wlds +                                       \
          (((w * 12 + (1 * 3 + (G)) * 2 + kk) << 10) + lane * 16));            \
      acc[0][G] = mfma16(a[6 + kk], bf0, acc[0][G]);                           \
      acc[1][G] = mfma16(a[6 + kk], bf1, acc[1][G]);                           \
    }                                                                          \
  }

// FAST GRU layer. grid=8: dir=bx&1, samples sb=(bx>>1)*16. 512 thr = 8 waves.
// Wave w owns units [32w, 32w+32): unit tiles j=0,1 (u=32w+16j+c), gate rows
// g*256+32w+16j. W frags (j,g,kt): kt 0..5 pinned in VGPRs, kt 6,7 in LDS.
// gi arrives PRE-PERMUTED (gemm PERM); h-LDS cols / whh K / hout use the
// unit-pair permutation pi(u) = w*32 + c*2 + j, so h writes are packed u32
// and hout stores are coalesced dwords.
// z-gate acc init = gi_z; n-gate acc init = scaled bhh_n (MFMA accumulates on
// top) — removes 16 zero-inits + 16 adds per wave vs R12.
// bf16 path: h double-buffered (2x9216 B), ONE barrier/step.
template <typename GT>
__global__ __launch_bounds__(512, 2) void gru_fast_kernel(
    const GT* __restrict__ gi,               // staged-layout, bias folded
    const unsigned short* __restrict__ whh,  // [2][768][256] bf16, K pi-permuted
    const float* __restrict__ bhh,           // [2][768] raw
    unsigned short* __restrict__ hout) {     // [T*B][512] bf16, pi-permuted
  constexpr int E = (int)sizeof(GT);
  constexpr int CH = (E * 1536) / 1024;      // 16B granules per wave / 64 lanes
  constexpr bool DB = (E == 2);              // h dbuf only on bf16 path
  constexpr int HB = DB ? 18432 : 9216;      // h region bytes
  extern __shared__ __align__(16) char smem[];
  char* wlds = smem;                   // 8 waves * 12 frags * 1024 B = 98304
  char* hl   = smem + 98304;           // h bf16 [16][288] stride 576 (x2 if DB)
  char* glds = smem + 98304 + HB;      // staged gi: 8 waves * 1536*E B
  const int tid = threadIdx.x;
  const int lane = tid & 63;
  const int w = tid >> 6;   // 0..7
  const int c = lane & 15;
  const int q = lane >> 4;  // 0..3
  const int dir = blockIdx.x & 1;
  const int sb = (blockIdx.x >> 1) * 16;

  for (int i = tid; i < HB / 2; i += 512) ((unsigned short*)hl)[i] = 0;

  const int u0 = 32 * w + c;  // j=0 unit; j=1 is u0+16
  const float bhn0 = SN * bhh[dir * 768 + 512 + u0];
  const float bhn1 = SN * bhh[dir * 768 + 512 + u0 + 16];

  // ---- W preload: frag (j,g,kt): row = g*256 + 32w + 16j + c, k-positions
  // kt*32 + q*8 .. +8 (positions hold pi-permuted units; A side matches)
  const unsigned short* wb =
      whh + (size_t)dir * 196608 + (size_t)u0 * 256 + q * 8;
  u32x4 wv[2][3][6];
#pragma unroll
  for (int j = 0; j < 2; ++j)
#pragma unroll
    for (int g = 0; g < 3; ++g) {
      const unsigned short* p = wb + (size_t)(g * 256 + 16 * j) * 256;
#pragma unroll
      for (int kt = 0; kt < 6; ++kt) wv[j][g][kt] = *(const u32x4*)(p + kt * 32);
#pragma unroll
      for (int kk = 0; kk < 2; ++kk) {
        u32x4 tmp = *(const u32x4*)(p + (6 + kk) * 32);
        *(u32x4*)(wlds + (((w * 12 + (j * 3 + g) * 2 + kk) << 10) + lane * 16)) = tmp;
      }
    }
  // pin: make each frag an opaque asm def -> cannot be rematerialized in-loop
#pragma unroll
  for (int j = 0; j < 2; ++j)
#pragma unroll
    for (int g = 0; g < 3; ++g)
#pragma unroll
      for (int kt = 0; kt < 6; ++kt)
        asm volatile("" : "+v"(wv[j][g][kt]));

  float h0[4] = {0.f, 0.f, 0.f, 0.f}, h1[4] = {0.f, 0.f, 0.f, 0.f};

  // moving pointers; hout as u32 (pair) in permuted layout:
  // u32 index = row*256 + dir*128 + w*16 + c
  const int t0 = dir ? 999 : 0;
  unsigned int* hp = (unsigned int*)hout +
                     ((size_t)t0 * 64 + sb) * 256 + dir * 128 + w * 16 + c;
  const ptrdiff_t gstep = (dir ? -1 : 1) * (ptrdiff_t)(64 * 1536);
  const ptrdiff_t hstep = (dir ? -1 : 1) * (ptrdiff_t)(64 * 256);

  // ---- staged-gi: this wave's region & global slice pointer ----
  char* gdw = glds + w * (1536 * E);
  const size_t slot0 =
      (size_t)t0 * 64 + (size_t)((blockIdx.x >> 1) * 2 + dir) * 8 + w;
  const GT* gp2 = gi + slot0 * 1536 + (size_t)lane * (16 / E);
  // prologue: stage t0's slice (CH linear 1KB DMAs)
#pragma unroll
  for (int i = 0; i < CH; ++i)
    async_ld16(gp2 + i * (1024 / E), gdw + i * 1024);
  gp2 += gstep;

  __syncthreads();

  const char* habase = hl + c * 576 + q * 16;  // A-frag: sample=c, pos=q*8 (+kt*32)
  const int hwb = q * 4 * 576 + w * 64 + c * 4;  // h-LDS write base (bytes)

  auto body = [&](int rd, int wr, bool first) {
    u32x4 a[8];
#pragma unroll
    for (int kt = 0; kt < 8; ++kt)
      a[kt] = *(const u32x4*)(habase + rd + kt * 64);
    if constexpr (!DB) lds_barrier();  // single buffer: A-reads before rewrite

    f32x4 acc[2][3];
    acc[0][0] = f32x4{0.f, 0.f, 0.f, 0.f};
    acc[1][0] = f32x4{0.f, 0.f, 0.f, 0.f};
    GBLOCK(0)  // r-gate MFMAs first

    // staged gi: DMA issued one step ago. Steady state: vmcnt queue =
    // [CH DMAs (older), 4 hout stores (newer)] -> vmcnt(4) drains only the
    // DMAs (in-order retirement), never waits on store completion.
    if (first) asm volatile("s_waitcnt vmcnt(0)" ::: "memory");
    else       asm volatile("s_waitcnt vmcnt(4)" ::: "memory");
    u32x4 raw[CH];
#pragma unroll
    for (int i = 0; i < CH; ++i)
      raw[i] = *(const u32x4*)(gdw + i * 1024 + lane * 16);

    // unpack: r-gate gi kept separate (its MFMA block already ran);
    // z-gate gi and scaled bhh_n become the acc INITS for GBLOCK(1)/(2).
    float pvr0[4], pvr1[4], pvn0[4], pvn1[4];
    if constexpr (E == 2) {
#pragma unroll
      for (int r = 0; r < 4; ++r) {
        const unsigned int dr0 = raw[0][r >> 1], dr1 = raw[0][2 + (r >> 1)];
        const unsigned int dz0 = raw[1][r >> 1], dz1 = raw[1][2 + (r >> 1)];
        const unsigned int dn0 = raw[2][r >> 1], dn1 = raw[2][2 + (r >> 1)];
        pvr0[r] = (r & 1) ? hi16(dr0) : lo16(dr0);
        pvr1[r] = (r & 1) ? hi16(dr1) : lo16(dr1);
        acc[0][1][r] = (r & 1) ? hi16(dz0) : lo16(dz0);
        acc[1][1][r] = (r & 1) ? hi16(dz1) : lo16(dz1);
        pvn0[r] = (r & 1) ? hi16(dn0) : lo16(dn0);
        pvn1[r] = (r & 1) ? hi16(dn1) : lo16(dn1);
        acc[0][2][r] = bhn0;
        acc[1][2][r] = bhn1;
      }
    } else {
#pragma unroll
      for (int r = 0; r < 4; ++r) {
        const f32x4 f0 = __builtin_bit_cast(f32x4, raw[0 + (r >> 1)]);
        const f32x4 f1 = __builtin_bit_cast(f32x4, raw[2 + (r >> 1)]);
        const f32x4 f2 = __builtin_bit_cast(f32x4, raw[4 + (r >> 1)]);
        pvr0[r] = f0[r & 1];
        pvr1[r] = f0[2 + (r & 1)];
        acc[0][1][r] = f1[r & 1];
        acc[1][1][r] = f1[2 + (r & 1)];
        pvn0[r] = f2[r & 1];
        pvn1[r] = f2[2 + (r & 1)];
        acc[0][2][r] = bhn0;
        acc[1][2][r] = bhn1;
      }
    }

    // r-gate trans chains overlap the n-gate MFMA block
    float rr0[4], rr1[4];
#pragma unroll
    for (int r = 0; r < 4; ++r) {
      rr0[r] = sigm2(pvr0[r] + acc[0][0][r]);
      rr1[r] = sigm2(pvr1[r] + acc[1][0][r]);
    }

    GBLOCK(2)  // n-gate MFMAs (acc pre-loaded with scaled bhh_n)

    float nn0[4], nn1[4];
#pragma unroll
    for (int r = 0; r < 4; ++r) {
      nn0[r] = tanh2(__builtin_fmaf(rr0[r], acc[0][2][r], pvn0[r]));
      nn1[r] = tanh2(__builtin_fmaf(rr1[r], acc[1][2][r], pvn1[r]));
    }

    GBLOCK(1)  // z-gate MFMAs (acc pre-loaded with gi_z)

    // own staged reads complete (lgkm) -> safe to overwrite with next DMA;
    // new DMA stays in flight across the barrier until next step's fence.
    asm volatile("s_waitcnt lgkmcnt(0)" ::: "memory");
#pragma unroll
    for (int i = 0; i < CH; ++i)
      async_ld16(gp2 + i * (1024 / E), gdw + i * 1024);
    gp2 += gstep;

    unsigned short* hls = (unsigned short*)(hl + wr);
#pragma unroll
    for (int r = 0; r < 4; ++r) {  // sample s = q*4+r ; C-row = q*4+reg
      const float zz0 = sigm2(acc[0][1][r]);
      const float hv0 = __builtin_fmaf(zz0, h0[r] - nn0[r], nn0[r]);
      h0[r] = hv0;
      const float zz1 = sigm2(acc[1][1][r]);
      const float hv1 = __builtin_fmaf(zz1, h1[r] - nn1[r], nn1[r]);
      h1[r] = hv1;
      const unsigned int pk = cvtpk(hv0, hv1);  // lo=unit u0 (j0), hi=u0+16
      *(unsigned int*)((char*)hls + hwb + r * 576) = pk;  // packed pair write
      hp[(size_t)(q * 4 + r) * 256] = pk;                 // coalesced dword
    }
    hp += hstep;
    lds_barrier();  // publish h writes (and, if !DB, protect next A-reads)
  };

  if constexpr (DB) {
    body(0, 9216, true);   // peeled: only prologue DMAs outstanding -> vmcnt(0)
    body(9216, 0, false);
    for (int it = 1; it < 500; ++it) {  // ping-pong, compile-time offsets
      body(0, 9216, false);
      body(9216, 0, false);
    }
  } else {
    body(0, 0, true);
    for (int step = 1; step < 1000; ++step) body(0, 0, false);
  }
  // drain the final (discarded) stage DMA before workgroup teardown
  asm volatile("s_waitcnt vmcnt(0)" ::: "memory");
}

// ---------------------------------------------------------------------------
// LEGACY GRU (fallback if big dynamic LDS unsupported) — linear gi/hout layout.
template <typename GT>
__global__ __launch_bounds__(1024) void gru_layer_kernel(
    const GT* __restrict__ gi, const unsigned short* __restrict__ whh,
    const float* __restrict__ bhh, unsigned short* __restrict__ hout) {
  __shared__ __align__(16) unsigned short hbf[16][264];
  __shared__ __align__(16) float gh[16][780];
  const int tid = threadIdx.x;
  const int lane = tid & 63;
  const int wv = tid >> 6;
  const int dir = blockIdx.x & 1;
  const int sb = (blockIdx.x >> 1) * 16;
  const int j = tid & 255;
  const int si = tid >> 8;

  float hreg[4] = {0.f, 0.f, 0.f, 0.f};
#pragma unroll
  for (int i = 0; i < 4; ++i) hbf[si + i * 4][j] = 0;

  const float bh_n = SN * bhh[dir * 768 + 512 + j];

  const unsigned short* wl = whh + (size_t)dir * 768 * 256 +
                             (size_t)(wv * 48 + (lane & 15)) * 256 +
                             ((lane >> 4) * 8);
  const char* habase = (const char*)hbf + (lane & 15) * 528 + ((lane >> 4) << 4);
  const int srow = (lane >> 4) * 4;

  __syncthreads();

  for (int step = 0; step < 1000; ++step) {
    const int t = dir ? (999 - step) : step;
    float p_ir[4], p_iz[4], p_in[4];
#pragma unroll
    for (int i = 0; i < 4; ++i) {
      const int s = si + i * 4;
      const size_t gib = ((size_t)t * 64 + (sb + s)) * 1536 + dir * 768 + j;
      p_ir[i] = gload(gi, gib);
      p_iz[i] = gload(gi, gib + 256);
      p_in[i] = gload(gi, gib + 512);
    }
    u32x4 a[8];
#pragma unroll
    for (int kt = 0; kt < 8; ++kt) a[kt] = *(const u32x4*)(habase + kt * 64);
#pragma unroll
    for (int ntd = 0; ntd < 3; ++ntd) {
      f32x4 acc = {0.f, 0.f, 0.f, 0.f};
#pragma unroll
      for (int kt = 0; kt < 8; ++kt) {
        u32x4 bfrag = *(const u32x4*)(wl + ntd * (16 * 256) + kt * 32);
        acc = mfma16(a[kt], bfrag, acc);
      }
      const int gcol = (wv * 3 + ntd) * 16 + (lane & 15);
#pragma unroll
      for (int r = 0; r < 4; ++r) gh[srow + r][gcol] = acc[r];
    }
    __syncthreads();
#pragma unroll
    for (int i = 0; i < 4; ++i) {
      const int s = si + i * 4;
      const float r = sigm2(p_ir[i] + gh[s][j]);
      const float z = sigm2(p_iz[i] + gh[s][256 + j]);
      const float n = tanh2(__builtin_fmaf(r, gh[s][512 + j] + bh_n, p_in[i]));
      const float h = __builtin_fmaf(z, hreg[i] - n, n);
      hreg[i] = h;
      const unsigned short hb = f2b(h);
      hbf[s][j] = hb;
      hout[((size_t)t * 64 + (sb + s)) * 512 + dir * 256 + j] = hb;
    }
    __syncthreads();
  }
}

// ---------------------------------------------------------------------------
__global__ void prefix_kernel(const int* __restrict__ raw,
                              int* __restrict__ pref, int* __restrict__ lens) {
  if (threadIdx.x == 0) {
    const int stride = (raw[1] == 0 && raw[3] == 0 && raw[5] == 0) ? 2 : 1;
    int a = 0;
    for (int b = 0; b < 64; ++b) {
      const int L = raw[b * stride];
      pref[b] = a;
      lens[b] = L;
      a += L;
    }
  }
}

// fc: dot over 512; both h2 and fcw share the same K-permutation (if any),
// so the linear dot product is permutation-invariant.
__global__ __launch_bounds__(256) void fc_kernel(
    const unsigned short* __restrict__ h2, const unsigned short* __restrict__ fcw,
    const float* __restrict__ fcb, const int* __restrict__ lens,
    const int* __restrict__ pref, float* __restrict__ out) {
  __shared__ __align__(16) unsigned short hrow[4][512];
  const int b = blockIdx.y;
  const int sub = threadIdx.x >> 6, lane = threadIdx.x & 63;
  const int t = blockIdx.x * 4 + sub;
  *(u32x4*)&hrow[sub][lane * 8] =
      *(const u32x4*)&h2[((size_t)t * 64 + b) * 512 + lane * 8];
  __syncthreads();
  const int len = lens[b];
  if (lane < 61 && t < len) {
    float acc = fcb[lane];
    const unsigned short* wr = fcw + (size_t)lane * 512;
#pragma unroll 4
    for (int k = 0; k < 512; k += 8) {
      u32x4 w4 = *(const u32x4*)(wr + k);
      u32x4 h4 = *(const u32x4*)(&hrow[sub][k]);
#pragma unroll
      for (int qq = 0; qq < 4; ++qq) {
        acc += __uint_as_float(w4[qq] << 16) * __uint_as_float(h4[qq] << 16);
        acc += __uint_as_float(w4[qq] & 0xffff0000u) * __uint_as_float(h4[qq] & 0xffff0000u);
      }
    }
    out[((size_t)pref[b] + t) * 61 + lane] = acc;
  }
}

// ---------------------------------------------------------------------------
template <typename GT>
static void run_pipeline(const float* batch, const int* lengths_raw,
                         const float* w_ih_l0, const float* w_hh_l0,
                         const float* b_ih_l0, const float* b_hh_l0,
                         const float* w_ih_l1, const float* w_hh_l1,
                         const float* b_ih_l1, const float* b_hh_l1,
                         const float* fc_w, const float* fc_b, float* out,
                         char* ws, hipStream_t stream) {
  size_t off = 0;
  auto alloc = [&](size_t bytes) -> char* {
    char* p = ws + off;
    off += (bytes + 255) & ~(size_t)255;
    return p;
  };
  char* pool = alloc((size_t)64000 * 512 * 2);  // xb/h1/h2 liveness-disjoint
  unsigned short* xb = (unsigned short*)pool;
  unsigned short* h1 = (unsigned short*)pool;
  unsigned short* h2 = (unsigned short*)pool;
  // +1 timestep slack: final (discarded) stage prefetch reads t=1000 / t=-1
  GT*             gi   = (GT*)alloc((size_t)64064 * 1536 * sizeof(GT));
  unsigned short* wih0 = (unsigned short*)alloc((size_t)1536 * 320 * 2);
  unsigned short* wih1 = (unsigned short*)alloc((size_t)1536 * 512 * 2);
  unsigned short* whh0 = (unsigned short*)alloc((size_t)1536 * 256 * 2);
  unsigned short* whh1 = (unsigned short*)alloc((size_t)1536 * 256 * 2);
  unsigned short* fcwb = (unsigned short*)alloc((size_t)61 * 512 * 2);
  float*          fb0  = (float*)alloc(1536 * 4);
  float*          fb1  = (float*)alloc(1536 * 4);
  int*            pref = (int*)alloc(256);
  int*            lens = (int*)alloc(256);

  // decide the fast path FIRST (cast kernels depend on it)
  const int HB = (sizeof(GT) == 2) ? 18432 : 9216;
  const int GRU_LDS = 98304 + HB + 8 * 1536 * (int)sizeof(GT);
  const bool big_lds =
      hipFuncSetAttribute(reinterpret_cast<const void*>(gru_fast_kernel<GT>),
                          hipFuncAttributeMaxDynamicSharedMemorySize,
                          GRU_LDS) == hipSuccess;

  auto castw_lin = [&](const float* s, unsigned short* d, int n, int in_dim) {
    cast_w_kernel<<<dim3((n + 255) / 256), dim3(256), 0, stream>>>(s, d, n, in_dim);
  };
  auto castw_perm = [&](const float* s, unsigned short* d, int n, int in_dim,
                        int scaled) {
    cast_w_perm_kernel<<<dim3((n + 255) / 256), dim3(256), 0, stream>>>(
        s, d, n, in_dim, scaled);
  };

  castw_lin(w_ih_l0, wih0, 2 * 768 * 320, 320);  // x side: never permuted
  if (big_lds) {
    // K-dims that contract against h (pi-permuted h layout)
    castw_perm(w_hh_l0, whh0, 2 * 768 * 256, 256, 1);
    castw_perm(w_hh_l1, whh1, 2 * 768 * 256, 256, 1);
    castw_perm(w_ih_l1, wih1, 2 * 768 * 512, 512, 1);
    castw_perm(fc_w, fcwb, 61 * 512, 512, 0);
  } else {
    castw_lin(w_hh_l0, whh0, 2 * 768 * 256, 256);
    castw_lin(w_hh_l1, whh1, 2 * 768 * 256, 256);
    castw_lin(w_ih_l1, wih1, 2 * 768 * 512, 512);
    cast_bf16_kernel<<<dim3((61 * 512 + 255) / 256), dim3(256), 0, stream>>>(
        fc_w, fcwb, 61 * 512);
  }
  bias_fuse_kernel<<<dim3(6), dim3(256), 0, stream>>>(b_ih_l0, b_hh_l0, fb0);
  bias_fuse_kernel<<<dim3(6), dim3(256), 0, stream>>>(b_ih_l1, b_hh_l1, fb1);

  transpose_x_kernel<<<dim3(1000, 64), dim3(320), 0, stream>>>(batch, xb);

  auto gemm = [&](const unsigned short* A, const unsigned short* W,
                  const float* fb, GT* Cc, int M, int N, int K) {
    if (big_lds)
      gemm_bt_kernel<GT, true><<<dim3(500, 12), dim3(256), 0, stream>>>(
          A, W, fb, Cc, M, N, K);
    else
      gemm_bt_kernel<GT, false><<<dim3(500, 12), dim3(256), 0, stream>>>(
          A, W, fb, Cc, M, N, K);
  };
  auto gru = [&](GT* g, unsigned short* w, const float* b, unsigned short* h) {
    if (big_lds)
      gru_fast_kernel<GT><<<dim3(8), dim3(512), GRU_LDS, stream>>>(g, w, b, h);
    else
      gru_layer_kernel<GT><<<dim3(8), dim3(1024), 0, stream>>>(g, w, b, h);
  };

  gemm(xb, wih0, fb0, gi, 64000, 1536, 320);
  gru(gi, whh0, b_hh_l0, h1);
  gemm(h1, wih1, fb1, gi, 64000, 1536, 512);
  gru(gi, whh1, b_hh_l1, h2);

  prefix_kernel<<<dim3(1), dim3(64), 0, stream>>>(lengths_raw, pref, lens);
  fc_kernel<<<dim3(250, 64), dim3(256), 0, stream>>>(h2, fcwb, fc_b, lens, pref, out);
}

extern "C" void kernel_launch(void* const* d_in, const int* in_sizes, int n_in,
                              void* d_out, int out_size, void* d_ws, size_t ws_size,
                              hipStream_t stream) {
  (void)in_sizes; (void)n_in; (void)out_size;
  const float* batch   = (const float*)d_in[0];
  const int*   lengths = (const int*)d_in[1];
  const float* w_ih_l0 = (const float*)d_in[2];
  const float* w_hh_l0 = (const float*)d_in[3];
  const float* b_ih_l0 = (const float*)d_in[4];
  const float* b_hh_l0 = (const float*)d_in[5];
  const float* w_ih_l1 = (const float*)d_in[6];
  const float* w_hh_l1 = (const float*)d_in[7];
  const float* b_ih_l1 = (const float*)d_in[8];
  const float* b_hh_l1 = (const float*)d_in[9];
  const float* fc_w    = (const float*)d_in[10];
  const float* fc_b    = (const float*)d_in[11];
  float* out = (float*)d_out;
  char* ws = (char*)d_ws;

  const size_t NEED_FP32 = 470000000ull;  // gi fp32 path peak (incl. slack)
  if (ws_size >= NEED_FP32) {
    run_pipeline<float>(batch, lengths, w_ih_l0, w_hh_l0, b_ih_l0, b_hh_l0,
                        w_ih_l1, w_hh_l1, b_ih_l1, b_hh_l1, fc_w, fc_b, out,
                        ws, stream);
  } else {
    run_pipeline<unsigned short>(batch, lengths, w_ih_l0, w_hh_l0, b_ih_l0,
                                 b_hh_l0, w_ih_l1, w_hh_l1, b_ih_l1, b_hh_l1,
                                 fc_w, fc_b, out, ws, stream);
  }
}

// Round 10
// 3634.776 us; speedup vs baseline: 1.0241x; 1.0241x over previous
//
#include <hip/hip_runtime.h>
#include <cstdint>
#include <cstddef>

// ---------------------------------------------------------------------------
// RNNModel: 2-layer bidirectional GRU (B=64, T=1000, H=256) + FC(512->61) +
// length-gather.
// Round 14 = exact restore of Round 12 (best verified: 1395us/dispatch,
// 3640us total). Round 13's two changes REVERTED with cause:
//  - GRU z/n acc-init put the MFMA blocks on the staged-gi unpack dependency
//    chain (MFMA issue stalled on lgkm+VALU): VALU work removed but dur +24us.
//  - GEMM 2-phase double-buffer halved GEMM occupancy (32KB LDS: 8->5
//    blocks/CU); implicit cross-block TLP already covered DMA latency.
// Structure summary (R12): unit-pair permutation pi(u)=w*32+c*2+j across
// h-LDS/whh-K/hout/wih1-K/fcw-K; 36 pinned W frags + 12/wave LDS; gate-split
// MFMA wall (r->n->z) with trans chains interleaved; gi staged via
// global_load_lds in GEMM-native layout; h dbuf single barrier (bf16);
// exp2-prescaled gates; counted vmcnt(4) fence; packed u32 h writes +
// coalesced dword hout stores.
// Floor analysis: MfmaUtil+VALUBusy(active) ~104% => both pipes saturated,
// serialized by the recurrence's all-to-all K=256 dep + M=16 MFMA granularity.
// ---------------------------------------------------------------------------

typedef __attribute__((ext_vector_type(8))) __bf16 bf16x8;
typedef __attribute__((ext_vector_type(4))) float f32x4;
typedef __attribute__((ext_vector_type(4))) unsigned int u32x4;

#define AS1 __attribute__((address_space(1)))
#define AS3 __attribute__((address_space(3)))

#define LOG2E 1.44269504089f
#define SRZ  (-1.44269504089f)   // scale for r,z rows
#define SN   (2.88539008177f)    // scale for n rows

__device__ __forceinline__ void async_ld16(const void* g, void* l) {
  __builtin_amdgcn_global_load_lds((const AS1 unsigned int*)g,
                                   (AS3 unsigned int*)l, 16, 0, 0);
}

__device__ __forceinline__ f32x4 mfma16(u32x4 a, u32x4 b, f32x4 c) {
  return __builtin_amdgcn_mfma_f32_16x16x32_bf16(
      __builtin_bit_cast(bf16x8, a), __builtin_bit_cast(bf16x8, b), c, 0, 0, 0);
}

__device__ __forceinline__ unsigned short f2b(float f) {  // f32 -> bf16 RNE
  unsigned int u = __float_as_uint(f);
  u += 0x7fffu + ((u >> 16) & 1u);
  return (unsigned short)(u >> 16);
}
__device__ __forceinline__ float b2f(unsigned short s) {
  return __uint_as_float(((unsigned int)s) << 16);
}
// packed f32 pair -> 2x bf16 in one u32 (lo = first arg), RNE
__device__ __forceinline__ unsigned int cvtpk(float lo, float hi) {
  unsigned int r;
  asm("v_cvt_pk_bf16_f32 %0, %1, %2" : "=v"(r) : "v"(lo), "v"(hi));
  return r;
}
__device__ __forceinline__ float lo16(unsigned int d) {
  return __uint_as_float(d << 16);
}
__device__ __forceinline__ float hi16(unsigned int d) {
  return __uint_as_float(d & 0xffff0000u);
}
__device__ __forceinline__ float gload(const float* p, size_t i) { return p[i]; }
__device__ __forceinline__ float gload(const unsigned short* p, size_t i) { return b2f(p[i]); }

// pre-scaled gate helpers (inputs already multiplied by SRZ / SN)
__device__ __forceinline__ float sigm2(float xs) {  // sigma(x), xs = -log2e*x
  return __builtin_amdgcn_rcpf(1.0f + __builtin_amdgcn_exp2f(xs));
}
__device__ __forceinline__ float tanh2(float ys) {  // tanh(y), ys = 2log2e*y
  return __builtin_fmaf(-2.0f,
      __builtin_amdgcn_rcpf(1.0f + __builtin_amdgcn_exp2f(ys)), 1.0f);
}

// lgkm-only barrier: don't drain vmcnt (stores + staged-gi DMA stay in flight)
__device__ __forceinline__ void lds_barrier() {
  asm volatile("" ::: "memory");
  __builtin_amdgcn_s_waitcnt(0xC07F);  // vmcnt=63, expcnt=7, lgkmcnt=0
  __builtin_amdgcn_s_barrier();
  asm volatile("" ::: "memory");
}

// ---------------------------------------------------------------------------
__global__ void cast_bf16_kernel(const float* __restrict__ src,
                                 unsigned short* __restrict__ dst, int n) {
  const int i = blockIdx.x * 256 + threadIdx.x;
  if (i < n) dst[i] = f2b(src[i]);
}

// weight cast with per-gate-row exp2 prescale. rows: [0,512) r,z ; [512,768) n
__global__ void cast_w_kernel(const float* __restrict__ src,
                              unsigned short* __restrict__ dst, int n,
                              int in_dim) {
  const int i = blockIdx.x * 256 + threadIdx.x;
  if (i < n) {
    const int row = (i / in_dim) % 768;
    const float s = (row < 512) ? SRZ : SN;
    dst[i] = f2b(s * src[i]);
  }
}

// weight cast with K-dim unit-pair permutation: dst position p within each
// 256-group holds src k = w*32 + j*16 + c where p = w*32 + c*2 + j.
// scaled!=0: per-gate-row exp2 prescale (rows mod 768).
__global__ void cast_w_perm_kernel(const float* __restrict__ src,
                                   unsigned short* __restrict__ dst, int n,
                                   int in_dim, int scaled) {
  const int i = blockIdx.x * 256 + threadIdx.x;
  if (i < n) {
    const int row = i / in_dim;
    const int p = i - row * in_dim;
    const int hi = p >> 8, pr = p & 255;
    const int w = pr >> 5, c2 = pr & 31;
    const int k = hi * 256 + w * 32 + (c2 & 1) * 16 + (c2 >> 1);
    float s = 1.0f;
    if (scaled) s = ((row % 768) < 512) ? SRZ : SN;
    dst[i] = f2b(s * src[(size_t)row * in_dim + k]);
  }
}

// fused GEMM bias: scaled (b_ih + b_hh) for r,z rows; scaled b_ih for n rows
__global__ void bias_fuse_kernel(const float* __restrict__ bih,
                                 const float* __restrict__ bhh,
                                 float* __restrict__ fb) {
  const int n = blockIdx.x * 256 + threadIdx.x;  // 0..1535
  if (n < 1536) {
    const int dir = n >> 9 >> 1 ? 1 : (n / 768);  // n/768
    const int rr = n - dir * 768;
    const float s = (rr < 512) ? SRZ : SN;
    float v = bih[dir * 768 + rr];
    if (rr < 512) v += bhh[dir * 768 + rr];
    fb[n] = s * v;
  }
}

// batch [B,T,8,40] -> x [T,B,320] bf16, x[t,b,f*8+c] = batch[b,t,c,f]
__global__ void transpose_x_kernel(const float* __restrict__ batch,
                                   unsigned short* __restrict__ xb) {
  const int t = blockIdx.x, b = blockIdx.y, i = threadIdx.x;  // block 320
  const float v = batch[((size_t)b * 1000 + t) * 320 + (i & 7) * 40 + (i >> 3)];
  xb[((size_t)t * 64 + b) * 320 + i] = f2b(v);
}

// ---------------------------------------------------------------------------
// C = A[M,K](bf16) @ W[N,K](bf16)^T + bias[N]. 128x128 tile, BK=32, 256 thr.
// PERM=false: C[M,N] row-major. PERM=true: GRU staged layout:
//   slot = t*64 + (sgrp*2+dir)*8 + ww,  ww = (unit/32) in 0..7
template <typename CT, bool PERM>
__global__ __launch_bounds__(256) void gemm_bt_kernel(
    const unsigned short* __restrict__ A, const unsigned short* __restrict__ W,
    const float* __restrict__ bias, CT* __restrict__ C, int M, int N, int K) {
  __shared__ __align__(16) unsigned short As[4096];
  __shared__ __align__(16) unsigned short Bs[4096];
  const int tid = threadIdx.x;
  const int lane = tid & 63;
  const int wv = tid >> 6;
  const int mBase = blockIdx.x * 128;
  const int nBase = blockIdx.y * 128;

  const int s0 = tid, s1 = tid + 256;
  const int r0 = ((s0 >> 6) << 4) | (s0 & 15), c0 = ((s0 >> 4) & 3) * 8;
  const int r1 = ((s1 >> 6) << 4) | (s1 & 15), c1 = ((s1 >> 4) & 3) * 8;

  const unsigned short* Arow0 = A + (size_t)(mBase + r0) * K + c0;
  const unsigned short* Arow1 = A + (size_t)(mBase + r1) * K + c1;
  const unsigned short* Wrow0 = W + (size_t)(nBase + r0) * K + c0;
  const unsigned short* Wrow1 = W + (size_t)(nBase + r1) * K + c1;

  char* lA = (char*)As;
  char* lB = (char*)Bs;
  char* dstA0 = lA + wv * 1024;
  char* dstA1 = lA + 4096 + wv * 1024;
  char* dstB0 = lB + wv * 1024;
  char* dstB1 = lB + 4096 + wv * 1024;

  f32x4 acc[4][4] = {};
  const int mh = (wv >> 1) * 64, nh = (wv & 1) * 64;
  const u32x4* As4 = (const u32x4*)As;
  const u32x4* Bs4 = (const u32x4*)Bs;

  for (int k0 = 0; k0 < K; k0 += 32) {
    __syncthreads();
    async_ld16(Arow0 + k0, dstA0);
    async_ld16(Arow1 + k0, dstA1);
    async_ld16(Wrow0 + k0, dstB0);
    async_ld16(Wrow1 + k0, dstB1);
    __syncthreads();
    u32x4 a[4], b[4];
#pragma unroll
    for (int mt = 0; mt < 4; ++mt) a[mt] = As4[((mh >> 4) + mt) * 64 + lane];
#pragma unroll
    for (int nt = 0; nt < 4; ++nt) b[nt] = Bs4[((nh >> 4) + nt) * 64 + lane];
#pragma unroll
    for (int mt = 0; mt < 4; ++mt)
#pragma unroll
      for (int nt = 0; nt < 4; ++nt)
        acc[mt][nt] = mfma16(a[mt], b[nt], acc[mt][nt]);
  }

  if constexpr (PERM) {
    const int t = (mBase + mh) >> 6;  // mBase+mh multiple of 64
#pragma unroll
    for (int p = 0; p < 2; ++p) {  // nt pair (2p -> j=0, 2p+1 -> j=1)
      const int nb0 = nBase + nh + p * 32;
      const int dir = (nb0 >= 768) ? 1 : 0;
      const int np = nb0 - dir * 768;
      const int g = np >> 8;
      const int ww = (np >> 5) & 7;
      const float bn0 = bias[nb0 + (lane & 15)];
      const float bn1 = bias[nb0 + 16 + (lane & 15)];
#pragma unroll
      for (int mt = 0; mt < 4; ++mt) {  // sample group = mt
        const size_t slot = (size_t)t * 64 + (size_t)(mt * 2 + dir) * 8 + ww;
        if constexpr (sizeof(CT) == 2) {
          u32x4 v;
          v[0] = cvtpk(acc[mt][2 * p][0] + bn0, acc[mt][2 * p][1] + bn0);
          v[1] = cvtpk(acc[mt][2 * p][2] + bn0, acc[mt][2 * p][3] + bn0);
          v[2] = cvtpk(acc[mt][2 * p + 1][0] + bn1, acc[mt][2 * p + 1][1] + bn1);
          v[3] = cvtpk(acc[mt][2 * p + 1][2] + bn1, acc[mt][2 * p + 1][3] + bn1);
          *(u32x4*)((unsigned short*)C + slot * 1536 + (size_t)g * 512 +
                    (size_t)lane * 8) = v;
        } else {
#pragma unroll
          for (int rs = 0; rs < 2; ++rs) {
            f32x4 v = {acc[mt][2 * p][2 * rs] + bn0,
                       acc[mt][2 * p][2 * rs + 1] + bn0,
                       acc[mt][2 * p + 1][2 * rs] + bn1,
                       acc[mt][2 * p + 1][2 * rs + 1] + bn1};
            *(f32x4*)((float*)C + slot * 1536 + (size_t)(g * 2 + rs) * 256 +
                      (size_t)lane * 4) = v;
          }
        }
      }
    }
  } else {
#pragma unroll
    for (int nt = 0; nt < 4; ++nt) {
      const int n = nBase + nh + nt * 16 + (lane & 15);
      const float bn = bias[n];
#pragma unroll
      for (int mt = 0; mt < 4; ++mt) {
        const int mrow = mBase + mh + mt * 16 + ((lane >> 4) << 2);
#pragma unroll
        for (int r = 0; r < 4; ++r) {
          const float v = acc[mt][nt][r] + bn;
          if constexpr (sizeof(CT) == 2)
            ((unsigned short*)C)[(size_t)(mrow + r) * N + n] = f2b(v);
          else
            ((float*)C)[(size_t)(mrow + r) * N + n] = v;
        }
      }
    }
  }
}

// ---------------------------------------------------------------------------
// one MFMA gate-block: 12 pinned-frag MFMAs + 4 LDS-tail MFMAs, G is a literal
#define GBLOCK(G)                                                              \
  {                                                                            \
    _Pragma("unroll") for (int kt = 0; kt < 6; ++kt) {                         \
      acc[0][G] = mfma16(a[kt], wv[0][G][kt], acc[0][G]);                      \
      acc[1][G] = mfma16(a[kt], wv[1][G][kt], acc[1][G]);                      \
    }                                                                          \
    _Pragma("unroll") for (int kk = 0; kk < 2; ++kk) {                         \
      u32x4 bf0 = *(const u32x4*)(wlds +                                       \
          (((w * 12 + (0 * 3 + (G)) * 2 + kk) << 10) + lane * 16));            \
      u32x4 bf1 = *(const u32x4*)(wlds +                                       \
          (((w * 12 + (1 * 3 + (G)) * 2 + kk) << 10) + lane * 16));            \
      acc[0][G] = mfma16(a[6 + kk], bf0, acc[0][G]);                           \
      acc[1][G] = mfma16(a[6 + kk], bf1, acc[1][G]);                           \
    }                                                                          \
  }

// FAST GRU layer. grid=8: dir=bx&1, samples sb=(bx>>1)*16. 512 thr = 8 waves.
// Wave w owns units [32w, 32w+32): unit tiles j=0,1 (u=32w+16j+c), gate rows
// g*256+32w+16j. W frags (j,g,kt): kt 0..5 pinned in VGPRs, kt 6,7 in LDS.
// gi arrives PRE-PERMUTED (gemm PERM); h-LDS cols / whh K / hout use the
// unit-pair permutation pi(u) = w*32 + c*2 + j, so h writes are packed u32
// and hout stores are coalesced dwords.
// bf16 path: h double-buffered (2x9216 B), ONE barrier/step.
template <typename GT>
__global__ __launch_bounds__(512, 2) void gru_fast_kernel(
    const GT* __restrict__ gi,               // staged-layout, bias folded
    const unsigned short* __restrict__ whh,  // [2][768][256] bf16, K pi-permuted
    const float* __restrict__ bhh,           // [2][768] raw
    unsigned short* __restrict__ hout) {     // [T*B][512] bf16, pi-permuted
  constexpr int E = (int)sizeof(GT);
  constexpr int CH = (E * 1536) / 1024;      // 16B granules per wave / 64 lanes
  constexpr bool DB = (E == 2);              // h dbuf only on bf16 path
  constexpr int HB = DB ? 18432 : 9216;      // h region bytes
  extern __shared__ __align__(16) char smem[];
  char* wlds = smem;                   // 8 waves * 12 frags * 1024 B = 98304
  char* hl   = smem + 98304;           // h bf16 [16][288] stride 576 (x2 if DB)
  char* glds = smem + 98304 + HB;      // staged gi: 8 waves * 1536*E B
  const int tid = threadIdx.x;
  const int lane = tid & 63;
  const int w = tid >> 6;   // 0..7
  const int c = lane & 15;
  const int q = lane >> 4;  // 0..3
  const int dir = blockIdx.x & 1;
  const int sb = (blockIdx.x >> 1) * 16;

  for (int i = tid; i < HB / 2; i += 512) ((unsigned short*)hl)[i] = 0;

  const int u0 = 32 * w + c;  // j=0 unit; j=1 is u0+16
  const float bhn0 = SN * bhh[dir * 768 + 512 + u0];
  const float bhn1 = SN * bhh[dir * 768 + 512 + u0 + 16];

  // ---- W preload: frag (j,g,kt): row = g*256 + 32w + 16j + c, k-positions
  // kt*32 + q*8 .. +8 (positions hold pi-permuted units; A side matches)
  const unsigned short* wb =
      whh + (size_t)dir * 196608 + (size_t)u0 * 256 + q * 8;
  u32x4 wv[2][3][6];
#pragma unroll
  for (int j = 0; j < 2; ++j)
#pragma unroll
    for (int g = 0; g < 3; ++g) {
      const unsigned short* p = wb + (size_t)(g * 256 + 16 * j) * 256;
#pragma unroll
      for (int kt = 0; kt < 6; ++kt) wv[j][g][kt] = *(const u32x4*)(p + kt * 32);
#pragma unroll
      for (int kk = 0; kk < 2; ++kk) {
        u32x4 tmp = *(const u32x4*)(p + (6 + kk) * 32);
        *(u32x4*)(wlds + (((w * 12 + (j * 3 + g) * 2 + kk) << 10) + lane * 16)) = tmp;
      }
    }
  // pin: make each frag an opaque asm def -> cannot be rematerialized in-loop
#pragma unroll
  for (int j = 0; j < 2; ++j)
#pragma unroll
    for (int g = 0; g < 3; ++g)
#pragma unroll
      for (int kt = 0; kt < 6; ++kt)
        asm volatile("" : "+v"(wv[j][g][kt]));

  float h0[4] = {0.f, 0.f, 0.f, 0.f}, h1[4] = {0.f, 0.f, 0.f, 0.f};

  // moving pointers; hout as u32 (pair) in permuted layout:
  // u32 index = row*256 + dir*128 + w*16 + c
  const int t0 = dir ? 999 : 0;
  unsigned int* hp = (unsigned int*)hout +
                     ((size_t)t0 * 64 + sb) * 256 + dir * 128 + w * 16 + c;
  const ptrdiff_t gstep = (dir ? -1 : 1) * (ptrdiff_t)(64 * 1536);
  const ptrdiff_t hstep = (dir ? -1 : 1) * (ptrdiff_t)(64 * 256);

  // ---- staged-gi: this wave's region & global slice pointer ----
  char* gdw = glds + w * (1536 * E);
  const size_t slot0 =
      (size_t)t0 * 64 + (size_t)((blockIdx.x >> 1) * 2 + dir) * 8 + w;
  const GT* gp2 = gi + slot0 * 1536 + (size_t)lane * (16 / E);
  // prologue: stage t0's slice (CH linear 1KB DMAs)
#pragma unroll
  for (int i = 0; i < CH; ++i)
    async_ld16(gp2 + i * (1024 / E), gdw + i * 1024);
  gp2 += gstep;

  __syncthreads();

  const char* habase = hl + c * 576 + q * 16;  // A-frag: sample=c, pos=q*8 (+kt*32)
  const int hwb = q * 4 * 576 + w * 64 + c * 4;  // h-LDS write base (bytes)

  auto body = [&](int rd, int wr, bool first) {
    u32x4 a[8];
#pragma unroll
    for (int kt = 0; kt < 8; ++kt)
      a[kt] = *(const u32x4*)(habase + rd + kt * 64);
    if constexpr (!DB) lds_barrier();  // single buffer: A-reads before rewrite

    f32x4 acc[2][3] = {};
    GBLOCK(0)  // r-gate MFMAs first

    // staged gi: DMA issued one step ago. Steady state: vmcnt queue =
    // [CH DMAs (older), 4 hout stores (newer)] -> vmcnt(4) drains only the
    // DMAs (in-order retirement), never waits on store completion.
    if (first) asm volatile("s_waitcnt vmcnt(0)" ::: "memory");
    else       asm volatile("s_waitcnt vmcnt(4)" ::: "memory");
    u32x4 raw[CH];
#pragma unroll
    for (int i = 0; i < CH; ++i)
      raw[i] = *(const u32x4*)(gdw + i * 1024 + lane * 16);

    float pvA[3][4], pvB[3][4];
    if constexpr (E == 2) {
#pragma unroll
      for (int g = 0; g < 3; ++g)
#pragma unroll
        for (int r = 0; r < 4; ++r) {
          const unsigned int d0 = raw[g][r >> 1];
          const unsigned int d1 = raw[g][2 + (r >> 1)];
          pvA[g][r] = (r & 1) ? hi16(d0) : lo16(d0);
          pvB[g][r] = (r & 1) ? hi16(d1) : lo16(d1);
        }
    } else {
#pragma unroll
      for (int g = 0; g < 3; ++g)
#pragma unroll
        for (int r = 0; r < 4; ++r) {
          const f32x4 f = __builtin_bit_cast(f32x4, raw[g * 2 + (r >> 1)]);
          pvA[g][r] = f[r & 1];
          pvB[g][r] = f[2 + (r & 1)];
        }
    }

    // r-gate trans chains overlap the n-gate MFMA block
    float rr0[4], rr1[4];
#pragma unroll
    for (int r = 0; r < 4; ++r) {
      rr0[r] = sigm2(pvA[0][r] + acc[0][0][r]);
      rr1[r] = sigm2(pvB[0][r] + acc[1][0][r]);
    }

    GBLOCK(2)  // n-gate MFMAs

    float nn0[4], nn1[4];
#pragma unroll
    for (int r = 0; r < 4; ++r) {
      nn0[r] = tanh2(__builtin_fmaf(rr0[r], acc[0][2][r] + bhn0, pvA[2][r]));
      nn1[r] = tanh2(__builtin_fmaf(rr1[r], acc[1][2][r] + bhn1, pvB[2][r]));
    }

    GBLOCK(1)  // z-gate MFMAs

    // own staged reads complete (lgkm) -> safe to overwrite with next DMA;
    // new DMA stays in flight across the barrier until next step's fence.
    asm volatile("s_waitcnt lgkmcnt(0)" ::: "memory");
#pragma unroll
    for (int i = 0; i < CH; ++i)
      async_ld16(gp2 + i * (1024 / E), gdw + i * 1024);
    gp2 += gstep;

    unsigned short* hls = (unsigned short*)(hl + wr);
#pragma unroll
    for (int r = 0; r < 4; ++r) {  // sample s = q*4+r ; C-row = q*4+reg
      const float zz0 = sigm2(pvA[1][r] + acc[0][1][r]);
      const float hv0 = __builtin_fmaf(zz0, h0[r] - nn0[r], nn0[r]);
      h0[r] = hv0;
      const float zz1 = sigm2(pvB[1][r] + acc[1][1][r]);
      const float hv1 = __builtin_fmaf(zz1, h1[r] - nn1[r], nn1[r]);
      h1[r] = hv1;
      const unsigned int pk = cvtpk(hv0, hv1);  // lo=unit u0 (j0), hi=u0+16
      *(unsigned int*)((char*)hls + hwb + r * 576) = pk;  // packed pair write
      hp[(size_t)(q * 4 + r) * 256] = pk;                 // coalesced dword
    }
    hp += hstep;
    lds_barrier();  // publish h writes (and, if !DB, protect next A-reads)
  };

  if constexpr (DB) {
    body(0, 9216, true);   // peeled: only prologue DMAs outstanding -> vmcnt(0)
    body(9216, 0, false);
    for (int it = 1; it < 500; ++it) {  // ping-pong, compile-time offsets
      body(0, 9216, false);
      body(9216, 0, false);
    }
  } else {
    body(0, 0, true);
    for (int step = 1; step < 1000; ++step) body(0, 0, false);
  }
  // drain the final (discarded) stage DMA before workgroup teardown
  asm volatile("s_waitcnt vmcnt(0)" ::: "memory");
}

// ---------------------------------------------------------------------------
// LEGACY GRU (fallback if big dynamic LDS unsupported) — linear gi/hout layout.
template <typename GT>
__global__ __launch_bounds__(1024) void gru_layer_kernel(
    const GT* __restrict__ gi, const unsigned short* __restrict__ whh,
    const float* __restrict__ bhh, unsigned short* __restrict__ hout) {
  __shared__ __align__(16) unsigned short hbf[16][264];
  __shared__ __align__(16) float gh[16][780];
  const int tid = threadIdx.x;
  const int lane = tid & 63;
  const int wv = tid >> 6;
  const int dir = blockIdx.x & 1;
  const int sb = (blockIdx.x >> 1) * 16;
  const int j = tid & 255;
  const int si = tid >> 8;

  float hreg[4] = {0.f, 0.f, 0.f, 0.f};
#pragma unroll
  for (int i = 0; i < 4; ++i) hbf[si + i * 4][j] = 0;

  const float bh_n = SN * bhh[dir * 768 + 512 + j];

  const unsigned short* wl = whh + (size_t)dir * 768 * 256 +
                             (size_t)(wv * 48 + (lane & 15)) * 256 +
                             ((lane >> 4) * 8);
  const char* habase = (const char*)hbf + (lane & 15) * 528 + ((lane >> 4) << 4);
  const int srow = (lane >> 4) * 4;

  __syncthreads();

  for (int step = 0; step < 1000; ++step) {
    const int t = dir ? (999 - step) : step;
    float p_ir[4], p_iz[4], p_in[4];
#pragma unroll
    for (int i = 0; i < 4; ++i) {
      const int s = si + i * 4;
      const size_t gib = ((size_t)t * 64 + (sb + s)) * 1536 + dir * 768 + j;
      p_ir[i] = gload(gi, gib);
      p_iz[i] = gload(gi, gib + 256);
      p_in[i] = gload(gi, gib + 512);
    }
    u32x4 a[8];
#pragma unroll
    for (int kt = 0; kt < 8; ++kt) a[kt] = *(const u32x4*)(habase + kt * 64);
#pragma unroll
    for (int ntd = 0; ntd < 3; ++ntd) {
      f32x4 acc = {0.f, 0.f, 0.f, 0.f};
#pragma unroll
      for (int kt = 0; kt < 8; ++kt) {
        u32x4 bfrag = *(const u32x4*)(wl + ntd * (16 * 256) + kt * 32);
        acc = mfma16(a[kt], bfrag, acc);
      }
      const int gcol = (wv * 3 + ntd) * 16 + (lane & 15);
#pragma unroll
      for (int r = 0; r < 4; ++r) gh[srow + r][gcol] = acc[r];
    }
    __syncthreads();
#pragma unroll
    for (int i = 0; i < 4; ++i) {
      const int s = si + i * 4;
      const float r = sigm2(p_ir[i] + gh[s][j]);
      const float z = sigm2(p_iz[i] + gh[s][256 + j]);
      const float n = tanh2(__builtin_fmaf(r, gh[s][512 + j] + bh_n, p_in[i]));
      const float h = __builtin_fmaf(z, hreg[i] - n, n);
      hreg[i] = h;
      const unsigned short hb = f2b(h);
      hbf[s][j] = hb;
      hout[((size_t)t * 64 + (sb + s)) * 512 + dir * 256 + j] = hb;
    }
    __syncthreads();
  }
}

// ---------------------------------------------------------------------------
__global__ void prefix_kernel(const int* __restrict__ raw,
                              int* __restrict__ pref, int* __restrict__ lens) {
  if (threadIdx.x == 0) {
    const int stride = (raw[1] == 0 && raw[3] == 0 && raw[5] == 0) ? 2 : 1;
    int a = 0;
    for (int b = 0; b < 64; ++b) {
      const int L = raw[b * stride];
      pref[b] = a;
      lens[b] = L;
      a += L;
    }
  }
}

// fc: dot over 512; both h2 and fcw share the same K-permutation (if any),
// so the linear dot product is permutation-invariant.
__global__ __launch_bounds__(256) void fc_kernel(
    const unsigned short* __restrict__ h2, const unsigned short* __restrict__ fcw,
    const float* __restrict__ fcb, const int* __restrict__ lens,
    const int* __restrict__ pref, float* __restrict__ out) {
  __shared__ __align__(16) unsigned short hrow[4][512];
  const int b = blockIdx.y;
  const int sub = threadIdx.x >> 6, lane = threadIdx.x & 63;
  const int t = blockIdx.x * 4 + sub;
  *(u32x4*)&hrow[sub][lane * 8] =
      *(const u32x4*)&h2[((size_t)t * 64 + b) * 512 + lane * 8];
  __syncthreads();
  const int len = lens[b];
  if (lane < 61 && t < len) {
    float acc = fcb[lane];
    const unsigned short* wr = fcw + (size_t)lane * 512;
#pragma unroll 4
    for (int k = 0; k < 512; k += 8) {
      u32x4 w4 = *(const u32x4*)(wr + k);
      u32x4 h4 = *(const u32x4*)(&hrow[sub][k]);
#pragma unroll
      for (int qq = 0; qq < 4; ++qq) {
        acc += __uint_as_float(w4[qq] << 16) * __uint_as_float(h4[qq] << 16);
        acc += __uint_as_float(w4[qq] & 0xffff0000u) * __uint_as_float(h4[qq] & 0xffff0000u);
      }
    }
    out[((size_t)pref[b] + t) * 61 + lane] = acc;
  }
}

// ---------------------------------------------------------------------------
template <typename GT>
static void run_pipeline(const float* batch, const int* lengths_raw,
                         const float* w_ih_l0, const float* w_hh_l0,
                         const float* b_ih_l0, const float* b_hh_l0,
                         const float* w_ih_l1, const float* w_hh_l1,
                         const float* b_ih_l1, const float* b_hh_l1,
                         const float* fc_w, const float* fc_b, float* out,
                         char* ws, hipStream_t stream) {
  size_t off = 0;
  auto alloc = [&](size_t bytes) -> char* {
    char* p = ws + off;
    off += (bytes + 255) & ~(size_t)255;
    return p;
  };
  char* pool = alloc((size_t)64000 * 512 * 2);  // xb/h1/h2 liveness-disjoint
  unsigned short* xb = (unsigned short*)pool;
  unsigned short* h1 = (unsigned short*)pool;
  unsigned short* h2 = (unsigned short*)pool;
  // +1 timestep slack: final (discarded) stage prefetch reads t=1000 / t=-1
  GT*             gi   = (GT*)alloc((size_t)64064 * 1536 * sizeof(GT));
  unsigned short* wih0 = (unsigned short*)alloc((size_t)1536 * 320 * 2);
  unsigned short* wih1 = (unsigned short*)alloc((size_t)1536 * 512 * 2);
  unsigned short* whh0 = (unsigned short*)alloc((size_t)1536 * 256 * 2);
  unsigned short* whh1 = (unsigned short*)alloc((size_t)1536 * 256 * 2);
  unsigned short* fcwb = (unsigned short*)alloc((size_t)61 * 512 * 2);
  float*          fb0  = (float*)alloc(1536 * 4);
  float*          fb1  = (float*)alloc(1536 * 4);
  int*            pref = (int*)alloc(256);
  int*            lens = (int*)alloc(256);

  // decide the fast path FIRST (cast kernels depend on it)
  const int HB = (sizeof(GT) == 2) ? 18432 : 9216;
  const int GRU_LDS = 98304 + HB + 8 * 1536 * (int)sizeof(GT);
  const bool big_lds =
      hipFuncSetAttribute(reinterpret_cast<const void*>(gru_fast_kernel<GT>),
                          hipFuncAttributeMaxDynamicSharedMemorySize,
                          GRU_LDS) == hipSuccess;

  auto castw_lin = [&](const float* s, unsigned short* d, int n, int in_dim) {
    cast_w_kernel<<<dim3((n + 255) / 256), dim3(256), 0, stream>>>(s, d, n, in_dim);
  };
  auto castw_perm = [&](const float* s, unsigned short* d, int n, int in_dim,
                        int scaled) {
    cast_w_perm_kernel<<<dim3((n + 255) / 256), dim3(256), 0, stream>>>(
        s, d, n, in_dim, scaled);
  };

  castw_lin(w_ih_l0, wih0, 2 * 768 * 320, 320);  // x side: never permuted
  if (big_lds) {
    // K-dims that contract against h (pi-permuted h layout)
    castw_perm(w_hh_l0, whh0, 2 * 768 * 256, 256, 1);
    castw_perm(w_hh_l1, whh1, 2 * 768 * 256, 256, 1);
    castw_perm(w_ih_l1, wih1, 2 * 768 * 512, 512, 1);
    castw_perm(fc_w, fcwb, 61 * 512, 512, 0);
  } else {
    castw_lin(w_hh_l0, whh0, 2 * 768 * 256, 256);
    castw_lin(w_hh_l1, whh1, 2 * 768 * 256, 256);
    castw_lin(w_ih_l1, wih1, 2 * 768 * 512, 512);
    cast_bf16_kernel<<<dim3((61 * 512 + 255) / 256), dim3(256), 0, stream>>>(
        fc_w, fcwb, 61 * 512);
  }
  bias_fuse_kernel<<<dim3(6), dim3(256), 0, stream>>>(b_ih_l0, b_hh_l0, fb0);
  bias_fuse_kernel<<<dim3(6), dim3(256), 0, stream>>>(b_ih_l1, b_hh_l1, fb1);

  transpose_x_kernel<<<dim3(1000, 64), dim3(320), 0, stream>>>(batch, xb);

  auto gemm = [&](const unsigned short* A, const unsigned short* W,
                  const float* fb, GT* Cc, int M, int N, int K) {
    if (big_lds)
      gemm_bt_kernel<GT, true><<<dim3(500, 12), dim3(256), 0, stream>>>(
          A, W, fb, Cc, M, N, K);
    else
      gemm_bt_kernel<GT, false><<<dim3(500, 12), dim3(256), 0, stream>>>(
          A, W, fb, Cc, M, N, K);
  };
  auto gru = [&](GT* g, unsigned short* w, const float* b, unsigned short* h) {
    if (big_lds)
      gru_fast_kernel<GT><<<dim3(8), dim3(512), GRU_LDS, stream>>>(g, w, b, h);
    else
      gru_layer_kernel<GT><<<dim3(8), dim3(1024), 0, stream>>>(g, w, b, h);
  };

  gemm(xb, wih0, fb0, gi, 64000, 1536, 320);
  gru(gi, whh0, b_hh_l0, h1);
  gemm(h1, wih1, fb1, gi, 64000, 1536, 512);
  gru(gi, whh1, b_hh_l1, h2);

  prefix_kernel<<<dim3(1), dim3(64), 0, stream>>>(lengths_raw, pref, lens);
  fc_kernel<<<dim3(250, 64), dim3(256), 0, stream>>>(h2, fcwb, fc_b, lens, pref, out);
}

extern "C" void kernel_launch(void* const* d_in, const int* in_sizes, int n_in,
                              void* d_out, int out_size, void* d_ws, size_t ws_size,
                              hipStream_t stream) {
  (void)in_sizes; (void)n_in; (void)out_size;
  const float* batch   = (const float*)d_in[0];
  const int*   lengths = (const int*)d_in[1];
  const float* w_ih_l0 = (const float*)d_in[2];
  const float* w_hh_l0 = (const float*)d_in[3];
  const float* b_ih_l0 = (const float*)d_in[4];
  const float* b_hh_l0 = (const float*)d_in[5];
  const float* w_ih_l1 = (const float*)d_in[6];
  const float* w_hh_l1 = (const float*)d_in[7];
  const float* b_ih_l1 = (const float*)d_in[8];
  const float* b_hh_l1 = (const float*)d_in[9];
  const float* fc_w    = (const float*)d_in[10];
  const float* fc_b    = (const float*)d_in[11];
  float* out = (float*)d_out;
  char* ws = (char*)d_ws;

  const size_t NEED_FP32 = 470000000ull;  // gi fp32 path peak (incl. slack)
  if (ws_size >= NEED_FP32) {
    run_pipeline<float>(batch, lengths, w_ih_l0, w_hh_l0, b_ih_l0, b_hh_l0,
                        w_ih_l1, w_hh_l1, b_ih_l1, b_hh_l1, fc_w, fc_b, out,
                        ws, stream);
  } else {
    run_pipeline<unsigned short>(batch, lengths, w_ih_l0, w_hh_l0, b_ih_l0,
                                 b_hh_l0, w_ih_l1, w_hh_l1, b_ih_l1, b_hh_l1,
                                 fc_w, fc_b, out, ws, stream);
  }
}